// Round 18
// baseline (175.055 us; speedup 1.0000x reference)
//
#include <hip/hip_runtime.h>
#include <math.h>

#define B_ 8
#define T_ 4096
#define H_ 1024
#define K_ 128
#define V_ 128
#define OUT_ 1024
#define NPROJ 512
#define M_ (B_*T_)          // 32768
#define CC 32               // chunk length
#define NC 128              // chunks per batch

typedef __attribute__((ext_vector_type(8))) short bf16x8;
typedef __attribute__((ext_vector_type(4))) float f32x4;

__device__ inline unsigned short f2bf(float f){
  union{float f; unsigned int u;} x; x.f = f;
  unsigned int r = x.u + 0x7fff + ((x.u>>16)&1);   // RNE
  return (unsigned short)(r>>16);
}
__device__ inline float bf2f(unsigned short u){
  union{unsigned int i; float f;} x; x.i = ((unsigned int)u)<<16; return x.f;
}

#define GL16(gp, lp) __builtin_amdgcn_global_load_lds(\
  (const __attribute__((address_space(1))) unsigned int*)(gp), \
  (__attribute__((address_space(3))) unsigned int*)(lp), 16, 0, 0)

#define MFMA16(a,b,c) __builtin_amdgcn_mfma_f32_16x16x32_bf16((a),(b),(c),0,0,0)

// ---------------- merged transpose+convert for both weights
__global__ __launch_bounds__(256)
void convT2(const float* __restrict__ Wp, const float* __restrict__ Wo,
            unsigned short* __restrict__ Wpt, unsigned short* __restrict__ Wot) {
  __shared__ float t[32][33];
  int tx = threadIdx.x & 31, ty = threadIdx.x >> 5;   // ty 0..7
  const float* src; unsigned short* dst; int Kd, N, n0, k0;
  int bid = blockIdx.x;
  if (bid < 512) { src = Wp; dst = Wpt; Kd = 1024; N = 512;
    n0 = (bid & 15)*32; k0 = (bid >> 4)*32; }
  else { int j = bid - 512; src = Wo; dst = Wot; Kd = 128; N = 1024;
    n0 = (j & 31)*32; k0 = (j >> 5)*32; }
  #pragma unroll
  for (int r=0;r<4;r++){
    int k = ty*4 + r;
    t[k][tx] = src[(long)(k0+k)*N + n0 + tx];
  }
  __syncthreads();
  #pragma unroll
  for (int r=0;r<4;r++){
    int n = ty*4 + r;
    dst[(long)(n0+n)*Kd + k0 + tx] = f2bf(t[tx][n]);
  }
}

// ---------------- proj MFMA GEMM v4 + T1 XCD-pairing (R14/R16 best), with
// relaxed launch bounds: (512,2) lets the allocator use up to ~128 VGPR while
// still fitting 2 blocks/CU (16 waves) — same occupancy, looser regalloc.
__global__ __launch_bounds__(512, 2)
void proj_mfma4(const float* __restrict__ A, const unsigned short* __restrict__ Bt,
                const float* __restrict__ bias,
                unsigned short* __restrict__ qbf, unsigned short* __restrict__ kbf,
                float* __restrict__ gf, unsigned short* __restrict__ vbf) {
  __shared__ unsigned short sA[128*72];   // 18 KB, stride 72
  __shared__ unsigned short sB[256*64];   // 32 KB, swizzled slots
  int tid = threadIdx.x, lane = tid & 63, wid = tid >> 6;
  int wm = wid >> 2, wn = wid & 3;
  int l16 = lane & 15, g8 = (lane >> 4) * 8;
  int id = blockIdx.x;
  int bx = (id >> 3) & 1;                 // j & 1
  int by = (id & 7)*32 + (id >> 4);       // xcd*32 + (j>>1), bijective
  long row0 = (long)by * 128;
  int col0 = bx * 256;

  int arow = tid >> 2, acol0 = (tid & 3) * 16;
  const float* Ab = A + (row0 + arow) * 1024 + acol0;
  int srowB = lane >> 3;
  int scolB = (((lane & 7) ^ (srowB & 7)) * 8);

  f32x4 acc[4][4];
  #pragma unroll
  for (int i=0;i<4;i++)
    #pragma unroll
    for (int j=0;j<4;j++) acc[i][j] = (f32x4){0.f,0.f,0.f,0.f};

  float4 ra[4];
  #define LDA(k0_) { _Pragma("unroll") \
    for (int j_=0;j_<4;j_++) ra[j_] = *(const float4*)(Ab + (k0_) + j_*4); }
  #define STA() { \
    unsigned short o_[16]; \
    _Pragma("unroll") \
    for (int j_=0;j_<4;j_++){ \
      o_[j_*4+0]=f2bf(ra[j_].x); o_[j_*4+1]=f2bf(ra[j_].y); \
      o_[j_*4+2]=f2bf(ra[j_].z); o_[j_*4+3]=f2bf(ra[j_].w); \
    } \
    *(uint4*)&sA[arow*72 + acol0]     = ((uint4*)o_)[0]; \
    *(uint4*)&sA[arow*72 + acol0 + 8] = ((uint4*)o_)[1]; \
  }
  #define STB(k0_) { _Pragma("unroll") \
    for (int i_=0;i_<4;i_++){ \
      int r_ = wid*32 + i_*8; \
      GL16(Bt + (long)(col0 + r_ + srowB)*1024 + (k0_) + scolB, &sB[r_*64]); \
    } }

  LDA(0);
  for (int t = 0; t < 16; ++t) {
    STA();
    STB(t*64);
    __syncthreads();                 // sA written (lgkm), sB landed (vmcnt)
    if (t < 15) { LDA(t*64 + 64); }  // prefetch next A under compute
    #pragma unroll
    for (int kk2 = 0; kk2 < 2; ++kk2) {
      int kk = kk2 * 32;
      bf16x8 af[4], bf[4];
      #pragma unroll
      for (int mi=0;mi<4;mi++)
        af[mi] = *(const bf16x8*)&sA[(wm*64 + mi*16 + l16)*72 + kk + g8];
      #pragma unroll
      for (int ni=0;ni<4;ni++){
        int brow = wn*64 + ni*16 + l16;
        int slot = ((kk + g8) >> 3) ^ (brow & 7);
        bf[ni] = *(const bf16x8*)&sB[brow*64 + slot*8];
      }
      #pragma unroll
      for (int mi=0;mi<4;mi++)
        #pragma unroll
        for (int ni=0;ni<4;ni++)
          acc[mi][ni] = MFMA16(af[mi], bf[ni], acc[mi][ni]);
    }
    __syncthreads();                 // compute done; also drains A prefetch
  }
  #undef LDA
  #undef STA
  #undef STB

  // epilogue: wave's 64-col strip -> segment seg of {q,k,g,v}
  int seg = bx*2 + (wn>>1);                  // 0..3, wave-uniform
  int cbase = (wn&1)*64;
  #pragma unroll
  for (int mi=0;mi<4;mi++){
    #pragma unroll
    for (int ni=0;ni<4;ni++){
      int c = cbase + ni*16 + l16;           // 0..127 within segment
      float bsv = bias[seg*128 + c];
      #pragma unroll
      for (int r=0;r<4;r++){
        long grow = row0 + wm*64 + mi*16 + (lane>>4)*4 + r;
        float v = acc[mi][ni][r] + bsv;
        long off = grow*128 + c;
        if (seg == 0)      qbf[off] = f2bf(v);
        else if (seg == 1) kbf[off] = f2bf(1.f/(1.f+__expf(-v)));
        else if (seg == 2) gf[off]  = 1.f/(1.f+__expf(-v));
        else               vbf[off] = f2bf(v);
      }
    }
  }
}

// ---------------- prep_cs: fused prep + chunkstate. grid (NC, B_), 256 thr.
__global__ __launch_bounds__(256)
void prep_cs(const float* __restrict__ gf, unsigned short* __restrict__ qbf,
             unsigned short* __restrict__ kbf, const unsigned short* __restrict__ vbf,
             unsigned short* __restrict__ vT, float* __restrict__ Gc,
             unsigned short* __restrict__ Ut) {
  __shared__ unsigned short kS[128][36];
  __shared__ unsigned short vS[128][36];
  __shared__ float gtot[2][128];
  int tid = threadIdx.x;
  int c = blockIdx.x, b = blockIdx.y;
  int k = tid & 127, half = tid >> 7;
  long base = ((long)b*T_ + (long)c*CC + half*16) * 128;

  float gloc[16];
  {
    float G = 1.f;
    #pragma unroll
    for (int t=0;t<16;++t){
      G *= gf[base + (long)t*128 + k];
      gloc[t] = G;
    }
    gtot[half][k] = G;
  }
  __syncthreads();
  float pre  = half ? gtot[0][k] : 1.f;
  float Gtot = gtot[0][k] * gtot[1][k];

  unsigned short kh[16], vv[16];
  #pragma unroll
  for (int t=0;t<16;++t){
    long off = base + (long)t*128 + k;
    float Gt = pre * gloc[t];
    float q = bf2f(qbf[off]);
    qbf[off] = f2bf(q*Gt);
    float kk = bf2f(kbf[off]);
    float ktl = kk/Gt;
    kbf[off] = f2bf(ktl);
    kh[t] = f2bf(ktl*Gtot);
    vv[t] = vbf[off];
  }
  *(uint4*)&kS[k][half*16]   = ((uint4*)kh)[0];
  *(uint4*)&kS[k][half*16+8] = ((uint4*)kh)[1];
  *(uint4*)&vS[k][half*16]   = ((uint4*)vv)[0];
  *(uint4*)&vS[k][half*16+8] = ((uint4*)vv)[1];
  long cb = (long)b*NC + c;
  if (half == 0) Gc[cb*128 + k] = Gtot;
  long tb = (cb*128 + k)*CC + half*16;
  *(uint4*)(vT + tb)     = ((uint4*)vv)[0];
  *(uint4*)(vT + tb + 8) = ((uint4*)vv)[1];
  __syncthreads();

  int lane = tid & 63, w = tid >> 6;
  int l16 = lane & 15, g8 = (lane >> 4) * 8;
  bf16x8 af[2], bfr[8];
  #pragma unroll
  for (int i=0;i<2;i++) af[i] = *(const bf16x8*)&vS[w*32 + i*16 + l16][g8];
  #pragma unroll
  for (int j=0;j<8;j++) bfr[j] = *(const bf16x8*)&kS[j*16 + l16][g8];
  #pragma unroll
  for (int i=0;i<2;i++){
    #pragma unroll
    for (int j=0;j<8;j++){
      f32x4 acc = (f32x4){0.f,0.f,0.f,0.f};
      acc = MFMA16(af[i], bfr[j], acc);
      int kcol = j*16 + l16;
      #pragma unroll
      for (int r=0;r<4;r++){
        int vrow = w*32 + i*16 + (lane>>4)*4 + r;
        Ut[cb*16384 + vrow*128 + kcol] = f2bf(acc[r]);
      }
    }
  }
}

// ---------------- seqstate two-level scan
__global__ __launch_bounds__(256)
void seqstate_a(const float* __restrict__ Gc, const unsigned short* __restrict__ Ut,
                float* __restrict__ segB, float* __restrict__ segG) {
  int idx = blockIdx.x*256 + threadIdx.x;    // 0..4095
  int s = blockIdx.y, b = blockIdx.z;
  int v = idx>>5, k0 = (idx&31)*4;
  float cell[4] = {0.f,0.f,0.f,0.f};
  float gp[4] = {1.f,1.f,1.f,1.f};
  long ub = (long)b*NC*16384 + (long)v*128 + k0;
  long gb = (long)b*NC*128 + k0;
  int c0 = s*16;
  #pragma unroll 4
  for (int c=c0; c<c0+16; ++c){
    uint2 u = *(const uint2*)(Ut + ub + (long)c*16384);
    float4 gc = *(const float4*)(Gc + gb + (long)c*128);
    cell[0] = fmaf(cell[0], gc.x, bf2f((unsigned short)(u.x & 0xffff)));
    cell[1] = fmaf(cell[1], gc.y, bf2f((unsigned short)(u.x >> 16)));
    cell[2] = fmaf(cell[2], gc.z, bf2f((unsigned short)(u.y & 0xffff)));
    cell[3] = fmaf(cell[3], gc.w, bf2f((unsigned short)(u.y >> 16)));
    gp[0] *= gc.x; gp[1] *= gc.y; gp[2] *= gc.z; gp[3] *= gc.w;
  }
  long sb = ((long)b*8 + s)*16384 + (long)v*128 + k0;
  *(float4*)(segB + sb) = make_float4(cell[0],cell[1],cell[2],cell[3]);
  if (v == 0)
    *(float4*)(segG + ((long)b*8 + s)*128 + k0) = make_float4(gp[0],gp[1],gp[2],gp[3]);
}

__global__ __launch_bounds__(256)
void seqstate_b(const float* __restrict__ Gc, unsigned short* __restrict__ Ut,
                const float* __restrict__ segB, const float* __restrict__ segG,
                float* __restrict__ fstate) {
  int idx = blockIdx.x*256 + threadIdx.x;    // 0..4095
  int s = blockIdx.y, b = blockIdx.z;
  int v = idx>>5, k0 = (idx&31)*4;
  float cell[4] = {0.f,0.f,0.f,0.f};
  for (int sp=0; sp<s; ++sp){
    float4 bg = *(const float4*)(segG + ((long)b*8 + sp)*128 + k0);
    float4 bb = *(const float4*)(segB + ((long)b*8 + sp)*16384 + (long)v*128 + k0);
    cell[0] = fmaf(cell[0], bg.x, bb.x);
    cell[1] = fmaf(cell[1], bg.y, bb.y);
    cell[2] = fmaf(cell[2], bg.z, bb.z);
    cell[3] = fmaf(cell[3], bg.w, bb.w);
  }
  long ub = (long)b*NC*16384 + (long)v*128 + k0;
  long gb = (long)b*NC*128 + k0;
  int c0 = s*16;
  #pragma unroll 4
  for (int c=c0; c<c0+16; ++c){
    uint2 u = *(const uint2*)(Ut + ub + (long)c*16384);
    float4 gc = *(const float4*)(Gc + gb + (long)c*128);
    unsigned short cb4[4] = {f2bf(cell[0]), f2bf(cell[1]), f2bf(cell[2]), f2bf(cell[3])};
    *(uint2*)(Ut + ub + (long)c*16384) = *(uint2*)cb4;   // cellT[c] (pre-update)
    cell[0] = fmaf(cell[0], gc.x, bf2f((unsigned short)(u.x & 0xffff)));
    cell[1] = fmaf(cell[1], gc.y, bf2f((unsigned short)(u.x >> 16)));
    cell[2] = fmaf(cell[2], gc.z, bf2f((unsigned short)(u.y & 0xffff)));
    cell[3] = fmaf(cell[3], gc.w, bf2f((unsigned short)(u.y >> 16)));
  }
  if (s == 7){
    #pragma unroll
    for (int j=0;j<4;j++)
      fstate[((long)b*128 + k0 + j)*128 + v] = cell[j];
  }
}

// ---------------- chunkout_out v2: GL16 staging (linear LDS + XOR-swizzled
// source + swizzled reads, rule 21), NT out stores.
__global__ __launch_bounds__(256)
void chunkout_out(const unsigned short* __restrict__ qbf, const unsigned short* __restrict__ kbf,
                  const unsigned short* __restrict__ vT, const unsigned short* __restrict__ cellT,
                  const unsigned short* __restrict__ Wot, const float* __restrict__ bo,
                  float* __restrict__ out) {
  __shared__ __align__(16) unsigned short qS[32*128];
  __shared__ __align__(16) unsigned short kS[32*128];
  __shared__ __align__(16) unsigned short cS[128*128];
  __shared__ __align__(16) unsigned short vS[128*32];
  __shared__ __align__(16) unsigned short pS[4][32][36];   // 9216 B; reused as oS[32][144]
  unsigned short (*oS)[144] = (unsigned short (*)[144])&pS[0][0][0];
  int tid = threadIdx.x, lane = tid&63, w = tid>>6;
  long cb = (long)blockIdx.y*NC + blockIdx.x;
  const unsigned short* qg = qbf + cb*4096;
  const unsigned short* kg = kbf + cb*4096;
  const unsigned short* vg = vT  + cb*4096;
  const unsigned short* cg = cellT + cb*16384;

  // frag index helpers (swizzled-on-read, matching pre-swizzled GL16 source)
  #define IDX128(row_, kks_, g8_) ((row_)*128 + (((((kks_)*4) + ((g8_)>>3)) ^ ((row_)&7))*8))
  #define IDXV(row_, g8_)   ((row_)*32 + (((((g8_)>>3)) ^ (((row_)>>1)&3))*8))

  // GL16 staging: dest linear (wave-uniform base + lane*16), source pre-swizzled
  {
    #pragma unroll
    for (int i=0;i<2;i++){
      int r0 = w*8 + i*4;
      int row = r0 + (lane>>4), sl = lane&15;
      long soff = (long)row*128 + ((sl ^ (row&7))*8);
      GL16(qg + soff, &qS[r0*128]);
      GL16(kg + soff, &kS[r0*128]);
    }
    #pragma unroll
    for (int i=0;i<8;i++){
      int r0 = w*32 + i*4;
      int row = r0 + (lane>>4), sl = lane&15;
      GL16(cg + (long)row*128 + ((sl ^ (row&7))*8), &cS[r0*128]);
    }
    #pragma unroll
    for (int i=0;i<2;i++){
      int r0 = w*32 + i*16;
      int row = r0 + (lane>>2), sl = lane&3;
      GL16(vg + (long)row*32 + ((sl ^ ((row>>1)&3))*8), &vS[r0*32]);
    }
  }
  __syncthreads();

  int l16 = lane&15, g = lane>>4, g8 = g*8;
  // S tiles: S2[s][t], compute (s0,t0),(s0,t1),(s1,t1)
  f32x4 s00 = (f32x4){0.f,0.f,0.f,0.f}, s01 = s00, s11 = s00;
  #pragma unroll
  for (int ks=0; ks<4; ++ks){
    bf16x8 ka = *(const bf16x8*)&kS[IDX128(l16, ks, g8)];
    bf16x8 kb = *(const bf16x8*)&kS[IDX128(16+l16, ks, g8)];
    bf16x8 qa = *(const bf16x8*)&qS[IDX128(l16, ks, g8)];
    bf16x8 qb = *(const bf16x8*)&qS[IDX128(16+l16, ks, g8)];
    s00 = MFMA16(ka, qa, s00);
    s01 = MFMA16(ka, qb, s01);
    s11 = MFMA16(kb, qb, s11);
  }
  // P[t][s] = masked S2, bf16. zero quadrant t<16, s>=16
  pS[w][l16][16 + 4*g + 0] = 0; pS[w][l16][16 + 4*g + 1] = 0;
  pS[w][l16][16 + 4*g + 2] = 0; pS[w][l16][16 + 4*g + 3] = 0;
  #pragma unroll
  for (int r=0;r<4;r++){
    int sl = 4*g + r;
    pS[w][l16][sl]       = (l16 >= sl) ? f2bf(s00[r]) : (unsigned short)0;
    pS[w][16+l16][sl]    = f2bf(s01[r]);
    pS[w][16+l16][16+sl] = (l16 >= sl) ? f2bf(s11[r]) : (unsigned short)0;
  }
  // O = P@V + Q~@cellT
  f32x4 o[2][2];
  #pragma unroll
  for (int i=0;i<2;i++)
    #pragma unroll
    for (int j=0;j<2;j++) o[i][j] = (f32x4){0.f,0.f,0.f,0.f};
  {
    bf16x8 p0 = *(const bf16x8*)&pS[w][l16][g8];
    bf16x8 p1 = *(const bf16x8*)&pS[w][16+l16][g8];
    bf16x8 v0 = *(const bf16x8*)&vS[IDXV(w*32 + l16, g8)];
    bf16x8 v1 = *(const bf16x8*)&vS[IDXV(w*32 + 16 + l16, g8)];
    o[0][0] = MFMA16(p0, v0, o[0][0]);
    o[0][1] = MFMA16(p0, v1, o[0][1]);
    o[1][0] = MFMA16(p1, v0, o[1][0]);
    o[1][1] = MFMA16(p1, v1, o[1][1]);
  }
  #pragma unroll
  for (int ks=0; ks<4; ++ks){
    bf16x8 qa = *(const bf16x8*)&qS[IDX128(l16, ks, g8)];
    bf16x8 qb = *(const bf16x8*)&qS[IDX128(16+l16, ks, g8)];
    bf16x8 c0 = *(const bf16x8*)&cS[IDX128(w*32 + l16, ks, g8)];
    bf16x8 c1 = *(const bf16x8*)&cS[IDX128(w*32 + 16 + l16, ks, g8)];
    o[0][0] = MFMA16(qa, c0, o[0][0]);
    o[0][1] = MFMA16(qa, c1, o[0][1]);
    o[1][0] = MFMA16(qb, c0, o[1][0]);
    o[1][1] = MFMA16(qb, c1, o[1][1]);
  }
  __syncthreads();                   // all waves done reading pS
  #pragma unroll
  for (int ti=0;ti<2;ti++)
    #pragma unroll
    for (int vi=0;vi<2;vi++)
      #pragma unroll
      for (int r=0;r<4;r++)
        oS[ti*16 + 4*g + r][w*32 + vi*16 + l16] = f2bf(o[ti][vi][r]);
  __syncthreads();

  // out phase: out[32 rows][1024] = oS(32x128) @ Wot^T(128x1024) + bo
  long rowb = (long)blockIdx.y*T_ + (long)blockIdx.x*CC;
  #pragma unroll
  for (int nh=0; nh<2; ++nh){
    f32x4 oc[2][8];
    #pragma unroll
    for (int mt=0;mt<2;mt++)
      #pragma unroll
      for (int nt=0;nt<8;nt++) oc[mt][nt] = (f32x4){0.f,0.f,0.f,0.f};
    #pragma unroll
    for (int ks=0; ks<4; ++ks){
      bf16x8 a0 = *(const bf16x8*)&oS[l16][ks*32+g8];
      bf16x8 a1 = *(const bf16x8*)&oS[16+l16][ks*32+g8];
      #pragma unroll
      for (int nt=0; nt<8; ++nt){
        int n = w*256 + nh*128 + nt*16 + l16;
        bf16x8 bw = *(const bf16x8*)(Wot + (long)n*128 + ks*32 + g8);
        oc[0][nt] = MFMA16(a0, bw, oc[0][nt]);
        oc[1][nt] = MFMA16(a1, bw, oc[1][nt]);
      }
    }
    #pragma unroll
    for (int mt=0; mt<2; ++mt)
      #pragma unroll
      for (int nt=0; nt<8; ++nt){
        int col = w*256 + nh*128 + nt*16 + l16;
        float bv = bo[col];
        #pragma unroll
        for (int r=0;r<4;r++){
          long row = rowb + mt*16 + g*4 + r;
          __builtin_nontemporal_store(oc[mt][nt][r] + bv, &out[row*OUT_ + col]);
        }
      }
  }
  #undef IDX128
  #undef IDXV
}

extern "C" void kernel_launch(void* const* d_in, const int* in_sizes, int n_in,
                              void* d_out, int out_size, void* d_ws, size_t ws_size,
                              hipStream_t stream) {
  const float* hidden = (const float*)d_in[0];
  const float* Wp     = (const float*)d_in[1];
  const float* bp     = (const float*)d_in[2];
  const float* Wo     = (const float*)d_in[3];
  const float* bo     = (const float*)d_in[4];
  float* out    = (float*)d_out;
  float* fstate = out + (long)M_ * OUT_;

  char* w = (char*)d_ws;
  unsigned short* vT    = (unsigned short*)w;                     // 8 MB
  float*          Gc    = (float*)(w + 8388608);                  // 0.5 MB
  unsigned short* Ut    = (unsigned short*)(w + 8912896);         // 32 MB (also cellT)
  float*          segB  = (float*)(w + 42467328);                 // 4 MB
  float*          segG  = (float*)(w + 46661632);                 // 32 KB
  // persistent region
  unsigned short* Wot = (unsigned short*)(w + 67108864);          // 0.25 MB
  unsigned short* Wpt = (unsigned short*)(w + 67371008);          // 1 MB
  unsigned short* qbf = (unsigned short*)(w + 68419584);          // 8 MB
  unsigned short* kbf = (unsigned short*)(w + 76808192);          // 8 MB
  unsigned short* vbf = (unsigned short*)(w + 85196800);          // 8 MB
  float*          gf  = (float*)(w + 93585408);                   // 16 MB

  convT2<<<640, 256, 0, stream>>>(Wp, Wo, Wpt, Wot);
  proj_mfma4<<<512, 512, 0, stream>>>(hidden, Wpt, bp, qbf, kbf, gf, vbf);
  prep_cs<<<dim3(NC, B_), 256, 0, stream>>>(gf, qbf, kbf, vbf, vT, Gc, Ut);
  seqstate_a<<<dim3(16, 8, B_), 256, 0, stream>>>(Gc, Ut, segB, segG);
  seqstate_b<<<dim3(16, 8, B_), 256, 0, stream>>>(Gc, Ut, segB, segG, fstate);
  chunkout_out<<<dim3(NC, B_), 256, 0, stream>>>(qbf, kbf, vT, Ut, Wot, bo, out);
}

// Round 19
// 156.301 us; speedup vs baseline: 1.1200x; 1.1200x over previous
//
#include <hip/hip_runtime.h>
#include <math.h>

#define B_ 8
#define T_ 4096
#define H_ 1024
#define K_ 128
#define V_ 128
#define OUT_ 1024
#define NPROJ 512
#define M_ (B_*T_)          // 32768
#define CC 32               // chunk length
#define NC 128              // chunks per batch

typedef __attribute__((ext_vector_type(8))) short bf16x8;
typedef __attribute__((ext_vector_type(4))) float f32x4;

__device__ inline unsigned short f2bf(float f){
  union{float f; unsigned int u;} x; x.f = f;
  unsigned int r = x.u + 0x7fff + ((x.u>>16)&1);   // RNE
  return (unsigned short)(r>>16);
}
__device__ inline float bf2f(unsigned short u){
  union{unsigned int i; float f;} x; x.i = ((unsigned int)u)<<16; return x.f;
}

#define GL16(gp, lp) __builtin_amdgcn_global_load_lds(\
  (const __attribute__((address_space(1))) unsigned int*)(gp), \
  (__attribute__((address_space(3))) unsigned int*)(lp), 16, 0, 0)

#define MFMA16(a,b,c) __builtin_amdgcn_mfma_f32_16x16x32_bf16((a),(b),(c),0,0,0)

// ---------------- merged transpose+convert for both weights
__global__ __launch_bounds__(256)
void convT2(const float* __restrict__ Wp, const float* __restrict__ Wo,
            unsigned short* __restrict__ Wpt, unsigned short* __restrict__ Wot) {
  __shared__ float t[32][33];
  int tx = threadIdx.x & 31, ty = threadIdx.x >> 5;   // ty 0..7
  const float* src; unsigned short* dst; int Kd, N, n0, k0;
  int bid = blockIdx.x;
  if (bid < 512) { src = Wp; dst = Wpt; Kd = 1024; N = 512;
    n0 = (bid & 15)*32; k0 = (bid >> 4)*32; }
  else { int j = bid - 512; src = Wo; dst = Wot; Kd = 128; N = 1024;
    n0 = (j & 31)*32; k0 = (j >> 5)*32; }
  #pragma unroll
  for (int r=0;r<4;r++){
    int k = ty*4 + r;
    t[k][tx] = src[(long)(k0+k)*N + n0 + tx];
  }
  __syncthreads();
  #pragma unroll
  for (int r=0;r<4;r++){
    int n = ty*4 + r;
    dst[(long)(n0+n)*Kd + k0 + tx] = f2bf(t[tx][n]);
  }
}

// ---------------- proj MFMA GEMM v4 + T1 XCD-pairing (R14/R16 best, final)
// BM=128, BN=256, BK=64, 512 thr, (512,4) => 64 VGPR, 2 blocks/CU (load-bearing:
// inter-block overlap is what hides the 2-barrier drain; R18 proved (512,2)
// drops to 1 blk/CU and regresses). Grid 512, XCD-paired (A panel L2-hot).
__global__ __launch_bounds__(512, 4)
void proj_mfma4(const float* __restrict__ A, const unsigned short* __restrict__ Bt,
                const float* __restrict__ bias,
                unsigned short* __restrict__ qbf, unsigned short* __restrict__ kbf,
                float* __restrict__ gf, unsigned short* __restrict__ vbf) {
  __shared__ unsigned short sA[128*72];   // 18 KB, stride 72
  __shared__ unsigned short sB[256*64];   // 32 KB, swizzled slots
  int tid = threadIdx.x, lane = tid & 63, wid = tid >> 6;
  int wm = wid >> 2, wn = wid & 3;
  int l16 = lane & 15, g8 = (lane >> 4) * 8;
  int id = blockIdx.x;
  int bx = (id >> 3) & 1;                 // j & 1
  int by = (id & 7)*32 + (id >> 4);       // xcd*32 + (j>>1), bijective
  long row0 = (long)by * 128;
  int col0 = bx * 256;

  int arow = tid >> 2, acol0 = (tid & 3) * 16;
  const float* Ab = A + (row0 + arow) * 1024 + acol0;
  int srowB = lane >> 3;
  int scolB = (((lane & 7) ^ (srowB & 7)) * 8);

  f32x4 acc[4][4];
  #pragma unroll
  for (int i=0;i<4;i++)
    #pragma unroll
    for (int j=0;j<4;j++) acc[i][j] = (f32x4){0.f,0.f,0.f,0.f};

  float4 ra[4];
  #define LDA(k0_) { _Pragma("unroll") \
    for (int j_=0;j_<4;j_++) ra[j_] = *(const float4*)(Ab + (k0_) + j_*4); }
  #define STA() { \
    unsigned short o_[16]; \
    _Pragma("unroll") \
    for (int j_=0;j_<4;j_++){ \
      o_[j_*4+0]=f2bf(ra[j_].x); o_[j_*4+1]=f2bf(ra[j_].y); \
      o_[j_*4+2]=f2bf(ra[j_].z); o_[j_*4+3]=f2bf(ra[j_].w); \
    } \
    *(uint4*)&sA[arow*72 + acol0]     = ((uint4*)o_)[0]; \
    *(uint4*)&sA[arow*72 + acol0 + 8] = ((uint4*)o_)[1]; \
  }
  #define STB(k0_) { _Pragma("unroll") \
    for (int i_=0;i_<4;i_++){ \
      int r_ = wid*32 + i_*8; \
      GL16(Bt + (long)(col0 + r_ + srowB)*1024 + (k0_) + scolB, &sB[r_*64]); \
    } }

  LDA(0);
  for (int t = 0; t < 16; ++t) {
    STA();
    STB(t*64);
    __syncthreads();                 // sA written (lgkm), sB landed (vmcnt)
    if (t < 15) { LDA(t*64 + 64); }  // prefetch next A under compute
    #pragma unroll
    for (int kk2 = 0; kk2 < 2; ++kk2) {
      int kk = kk2 * 32;
      bf16x8 af[4], bf[4];
      #pragma unroll
      for (int mi=0;mi<4;mi++)
        af[mi] = *(const bf16x8*)&sA[(wm*64 + mi*16 + l16)*72 + kk + g8];
      #pragma unroll
      for (int ni=0;ni<4;ni++){
        int brow = wn*64 + ni*16 + l16;
        int slot = ((kk + g8) >> 3) ^ (brow & 7);
        bf[ni] = *(const bf16x8*)&sB[brow*64 + slot*8];
      }
      #pragma unroll
      for (int mi=0;mi<4;mi++)
        #pragma unroll
        for (int ni=0;ni<4;ni++)
          acc[mi][ni] = MFMA16(af[mi], bf[ni], acc[mi][ni]);
    }
    __syncthreads();                 // compute done; also drains A prefetch
  }
  #undef LDA
  #undef STA
  #undef STB

  // epilogue: wave's 64-col strip -> segment seg of {q,k,g,v}
  int seg = bx*2 + (wn>>1);                  // 0..3, wave-uniform
  int cbase = (wn&1)*64;
  #pragma unroll
  for (int mi=0;mi<4;mi++){
    #pragma unroll
    for (int ni=0;ni<4;ni++){
      int c = cbase + ni*16 + l16;           // 0..127 within segment
      float bsv = bias[seg*128 + c];
      #pragma unroll
      for (int r=0;r<4;r++){
        long grow = row0 + wm*64 + mi*16 + (lane>>4)*4 + r;
        float v = acc[mi][ni][r] + bsv;
        long off = grow*128 + c;
        if (seg == 0)      qbf[off] = f2bf(v);
        else if (seg == 1) kbf[off] = f2bf(1.f/(1.f+__expf(-v)));
        else if (seg == 2) gf[off]  = 1.f/(1.f+__expf(-v));
        else               vbf[off] = f2bf(v);
      }
    }
  }
}

// ---------------- prep_cs: fused prep + chunkstate. grid (NC, B_), 256 thr.
__global__ __launch_bounds__(256)
void prep_cs(const float* __restrict__ gf, unsigned short* __restrict__ qbf,
             unsigned short* __restrict__ kbf, const unsigned short* __restrict__ vbf,
             unsigned short* __restrict__ vT, float* __restrict__ Gc,
             unsigned short* __restrict__ Ut) {
  __shared__ unsigned short kS[128][36];
  __shared__ unsigned short vS[128][36];
  __shared__ float gtot[2][128];
  int tid = threadIdx.x;
  int c = blockIdx.x, b = blockIdx.y;
  int k = tid & 127, half = tid >> 7;
  long base = ((long)b*T_ + (long)c*CC + half*16) * 128;

  float gloc[16];
  {
    float G = 1.f;
    #pragma unroll
    for (int t=0;t<16;++t){
      G *= gf[base + (long)t*128 + k];
      gloc[t] = G;
    }
    gtot[half][k] = G;
  }
  __syncthreads();
  float pre  = half ? gtot[0][k] : 1.f;
  float Gtot = gtot[0][k] * gtot[1][k];

  unsigned short kh[16], vv[16];
  #pragma unroll
  for (int t=0;t<16;++t){
    long off = base + (long)t*128 + k;
    float Gt = pre * gloc[t];
    float q = bf2f(qbf[off]);
    qbf[off] = f2bf(q*Gt);
    float kk = bf2f(kbf[off]);
    float ktl = kk/Gt;
    kbf[off] = f2bf(ktl);
    kh[t] = f2bf(ktl*Gtot);
    vv[t] = vbf[off];
  }
  *(uint4*)&kS[k][half*16]   = ((uint4*)kh)[0];
  *(uint4*)&kS[k][half*16+8] = ((uint4*)kh)[1];
  *(uint4*)&vS[k][half*16]   = ((uint4*)vv)[0];
  *(uint4*)&vS[k][half*16+8] = ((uint4*)vv)[1];
  long cb = (long)b*NC + c;
  if (half == 0) Gc[cb*128 + k] = Gtot;
  long tb = (cb*128 + k)*CC + half*16;
  *(uint4*)(vT + tb)     = ((uint4*)vv)[0];
  *(uint4*)(vT + tb + 8) = ((uint4*)vv)[1];
  __syncthreads();

  int lane = tid & 63, w = tid >> 6;
  int l16 = lane & 15, g8 = (lane >> 4) * 8;
  bf16x8 af[2], bfr[8];
  #pragma unroll
  for (int i=0;i<2;i++) af[i] = *(const bf16x8*)&vS[w*32 + i*16 + l16][g8];
  #pragma unroll
  for (int j=0;j<8;j++) bfr[j] = *(const bf16x8*)&kS[j*16 + l16][g8];
  #pragma unroll
  for (int i=0;i<2;i++){
    #pragma unroll
    for (int j=0;j<8;j++){
      f32x4 acc = (f32x4){0.f,0.f,0.f,0.f};
      acc = MFMA16(af[i], bfr[j], acc);
      int kcol = j*16 + l16;
      #pragma unroll
      for (int r=0;r<4;r++){
        int vrow = w*32 + i*16 + (lane>>4)*4 + r;
        Ut[cb*16384 + vrow*128 + kcol] = f2bf(acc[r]);
      }
    }
  }
}

// ---------------- seqstate two-level scan
__global__ __launch_bounds__(256)
void seqstate_a(const float* __restrict__ Gc, const unsigned short* __restrict__ Ut,
                float* __restrict__ segB, float* __restrict__ segG) {
  int idx = blockIdx.x*256 + threadIdx.x;    // 0..4095
  int s = blockIdx.y, b = blockIdx.z;
  int v = idx>>5, k0 = (idx&31)*4;
  float cell[4] = {0.f,0.f,0.f,0.f};
  float gp[4] = {1.f,1.f,1.f,1.f};
  long ub = (long)b*NC*16384 + (long)v*128 + k0;
  long gb = (long)b*NC*128 + k0;
  int c0 = s*16;
  #pragma unroll 4
  for (int c=c0; c<c0+16; ++c){
    uint2 u = *(const uint2*)(Ut + ub + (long)c*16384);
    float4 gc = *(const float4*)(Gc + gb + (long)c*128);
    cell[0] = fmaf(cell[0], gc.x, bf2f((unsigned short)(u.x & 0xffff)));
    cell[1] = fmaf(cell[1], gc.y, bf2f((unsigned short)(u.x >> 16)));
    cell[2] = fmaf(cell[2], gc.z, bf2f((unsigned short)(u.y & 0xffff)));
    cell[3] = fmaf(cell[3], gc.w, bf2f((unsigned short)(u.y >> 16)));
    gp[0] *= gc.x; gp[1] *= gc.y; gp[2] *= gc.z; gp[3] *= gc.w;
  }
  long sb = ((long)b*8 + s)*16384 + (long)v*128 + k0;
  *(float4*)(segB + sb) = make_float4(cell[0],cell[1],cell[2],cell[3]);
  if (v == 0)
    *(float4*)(segG + ((long)b*8 + s)*128 + k0) = make_float4(gp[0],gp[1],gp[2],gp[3]);
}

__global__ __launch_bounds__(256)
void seqstate_b(const float* __restrict__ Gc, unsigned short* __restrict__ Ut,
                const float* __restrict__ segB, const float* __restrict__ segG,
                float* __restrict__ fstate) {
  int idx = blockIdx.x*256 + threadIdx.x;    // 0..4095
  int s = blockIdx.y, b = blockIdx.z;
  int v = idx>>5, k0 = (idx&31)*4;
  float cell[4] = {0.f,0.f,0.f,0.f};
  for (int sp=0; sp<s; ++sp){
    float4 bg = *(const float4*)(segG + ((long)b*8 + sp)*128 + k0);
    float4 bb = *(const float4*)(segB + ((long)b*8 + sp)*16384 + (long)v*128 + k0);
    cell[0] = fmaf(cell[0], bg.x, bb.x);
    cell[1] = fmaf(cell[1], bg.y, bb.y);
    cell[2] = fmaf(cell[2], bg.z, bb.z);
    cell[3] = fmaf(cell[3], bg.w, bb.w);
  }
  long ub = (long)b*NC*16384 + (long)v*128 + k0;
  long gb = (long)b*NC*128 + k0;
  int c0 = s*16;
  #pragma unroll 4
  for (int c=c0; c<c0+16; ++c){
    uint2 u = *(const uint2*)(Ut + ub + (long)c*16384);
    float4 gc = *(const float4*)(Gc + gb + (long)c*128);
    unsigned short cb4[4] = {f2bf(cell[0]), f2bf(cell[1]), f2bf(cell[2]), f2bf(cell[3])};
    *(uint2*)(Ut + ub + (long)c*16384) = *(uint2*)cb4;   // cellT[c] (pre-update)
    cell[0] = fmaf(cell[0], gc.x, bf2f((unsigned short)(u.x & 0xffff)));
    cell[1] = fmaf(cell[1], gc.y, bf2f((unsigned short)(u.x >> 16)));
    cell[2] = fmaf(cell[2], gc.z, bf2f((unsigned short)(u.y & 0xffff)));
    cell[3] = fmaf(cell[3], gc.w, bf2f((unsigned short)(u.y >> 16)));
  }
  if (s == 7){
    #pragma unroll
    for (int j=0;j<4;j++)
      fstate[((long)b*128 + k0 + j)*128 + v] = cell[j];
  }
}

// ---------------- chunkout_out v2: GL16 staging (linear LDS + XOR-swizzled
// source + swizzled reads, rule 21), NT out stores.
__global__ __launch_bounds__(256)
void chunkout_out(const unsigned short* __restrict__ qbf, const unsigned short* __restrict__ kbf,
                  const unsigned short* __restrict__ vT, const unsigned short* __restrict__ cellT,
                  const unsigned short* __restrict__ Wot, const float* __restrict__ bo,
                  float* __restrict__ out) {
  __shared__ __align__(16) unsigned short qS[32*128];
  __shared__ __align__(16) unsigned short kS[32*128];
  __shared__ __align__(16) unsigned short cS[128*128];
  __shared__ __align__(16) unsigned short vS[128*32];
  __shared__ __align__(16) unsigned short pS[4][32][36];   // 9216 B; reused as oS[32][144]
  unsigned short (*oS)[144] = (unsigned short (*)[144])&pS[0][0][0];
  int tid = threadIdx.x, lane = tid&63, w = tid>>6;
  long cb = (long)blockIdx.y*NC + blockIdx.x;
  const unsigned short* qg = qbf + cb*4096;
  const unsigned short* kg = kbf + cb*4096;
  const unsigned short* vg = vT  + cb*4096;
  const unsigned short* cg = cellT + cb*16384;

  // frag index helpers (swizzled-on-read, matching pre-swizzled GL16 source)
  #define IDX128(row_, kks_, g8_) ((row_)*128 + (((((kks_)*4) + ((g8_)>>3)) ^ ((row_)&7))*8))
  #define IDXV(row_, g8_)   ((row_)*32 + (((((g8_)>>3)) ^ (((row_)>>1)&3))*8))

  // GL16 staging: dest linear (wave-uniform base + lane*16), source pre-swizzled
  {
    #pragma unroll
    for (int i=0;i<2;i++){
      int r0 = w*8 + i*4;
      int row = r0 + (lane>>4), sl = lane&15;
      long soff = (long)row*128 + ((sl ^ (row&7))*8);
      GL16(qg + soff, &qS[r0*128]);
      GL16(kg + soff, &kS[r0*128]);
    }
    #pragma unroll
    for (int i=0;i<8;i++){
      int r0 = w*32 + i*4;
      int row = r0 + (lane>>4), sl = lane&15;
      GL16(cg + (long)row*128 + ((sl ^ (row&7))*8), &cS[r0*128]);
    }
    #pragma unroll
    for (int i=0;i<2;i++){
      int r0 = w*32 + i*16;
      int row = r0 + (lane>>2), sl = lane&3;
      GL16(vg + (long)row*32 + ((sl ^ ((row>>1)&3))*8), &vS[r0*32]);
    }
  }
  __syncthreads();

  int l16 = lane&15, g = lane>>4, g8 = g*8;
  // S tiles: S2[s][t], compute (s0,t0),(s0,t1),(s1,t1)
  f32x4 s00 = (f32x4){0.f,0.f,0.f,0.f}, s01 = s00, s11 = s00;
  #pragma unroll
  for (int ks=0; ks<4; ++ks){
    bf16x8 ka = *(const bf16x8*)&kS[IDX128(l16, ks, g8)];
    bf16x8 kb = *(const bf16x8*)&kS[IDX128(16+l16, ks, g8)];
    bf16x8 qa = *(const bf16x8*)&qS[IDX128(l16, ks, g8)];
    bf16x8 qb = *(const bf16x8*)&qS[IDX128(16+l16, ks, g8)];
    s00 = MFMA16(ka, qa, s00);
    s01 = MFMA16(ka, qb, s01);
    s11 = MFMA16(kb, qb, s11);
  }
  // P[t][s] = masked S2, bf16. zero quadrant t<16, s>=16
  pS[w][l16][16 + 4*g + 0] = 0; pS[w][l16][16 + 4*g + 1] = 0;
  pS[w][l16][16 + 4*g + 2] = 0; pS[w][l16][16 + 4*g + 3] = 0;
  #pragma unroll
  for (int r=0;r<4;r++){
    int sl = 4*g + r;
    pS[w][l16][sl]       = (l16 >= sl) ? f2bf(s00[r]) : (unsigned short)0;
    pS[w][16+l16][sl]    = f2bf(s01[r]);
    pS[w][16+l16][16+sl] = (l16 >= sl) ? f2bf(s11[r]) : (unsigned short)0;
  }
  // O = P@V + Q~@cellT
  f32x4 o[2][2];
  #pragma unroll
  for (int i=0;i<2;i++)
    #pragma unroll
    for (int j=0;j<2;j++) o[i][j] = (f32x4){0.f,0.f,0.f,0.f};
  {
    bf16x8 p0 = *(const bf16x8*)&pS[w][l16][g8];
    bf16x8 p1 = *(const bf16x8*)&pS[w][16+l16][g8];
    bf16x8 v0 = *(const bf16x8*)&vS[IDXV(w*32 + l16, g8)];
    bf16x8 v1 = *(const bf16x8*)&vS[IDXV(w*32 + 16 + l16, g8)];
    o[0][0] = MFMA16(p0, v0, o[0][0]);
    o[0][1] = MFMA16(p0, v1, o[0][1]);
    o[1][0] = MFMA16(p1, v0, o[1][0]);
    o[1][1] = MFMA16(p1, v1, o[1][1]);
  }
  #pragma unroll
  for (int ks=0; ks<4; ++ks){
    bf16x8 qa = *(const bf16x8*)&qS[IDX128(l16, ks, g8)];
    bf16x8 qb = *(const bf16x8*)&qS[IDX128(16+l16, ks, g8)];
    bf16x8 c0 = *(const bf16x8*)&cS[IDX128(w*32 + l16, ks, g8)];
    bf16x8 c1 = *(const bf16x8*)&cS[IDX128(w*32 + 16 + l16, ks, g8)];
    o[0][0] = MFMA16(qa, c0, o[0][0]);
    o[0][1] = MFMA16(qa, c1, o[0][1]);
    o[1][0] = MFMA16(qb, c0, o[1][0]);
    o[1][1] = MFMA16(qb, c1, o[1][1]);
  }
  __syncthreads();                   // all waves done reading pS
  #pragma unroll
  for (int ti=0;ti<2;ti++)
    #pragma unroll
    for (int vi=0;vi<2;vi++)
      #pragma unroll
      for (int r=0;r<4;r++)
        oS[ti*16 + 4*g + r][w*32 + vi*16 + l16] = f2bf(o[ti][vi][r]);
  __syncthreads();

  // out phase: out[32 rows][1024] = oS(32x128) @ Wot^T(128x1024) + bo
  long rowb = (long)blockIdx.y*T_ + (long)blockIdx.x*CC;
  #pragma unroll
  for (int nh=0; nh<2; ++nh){
    f32x4 oc[2][8];
    #pragma unroll
    for (int mt=0;mt<2;mt++)
      #pragma unroll
      for (int nt=0;nt<8;nt++) oc[mt][nt] = (f32x4){0.f,0.f,0.f,0.f};
    #pragma unroll
    for (int ks=0; ks<4; ++ks){
      bf16x8 a0 = *(const bf16x8*)&oS[l16][ks*32+g8];
      bf16x8 a1 = *(const bf16x8*)&oS[16+l16][ks*32+g8];
      #pragma unroll
      for (int nt=0; nt<8; ++nt){
        int n = w*256 + nh*128 + nt*16 + l16;
        bf16x8 bw = *(const bf16x8*)(Wot + (long)n*128 + ks*32 + g8);
        oc[0][nt] = MFMA16(a0, bw, oc[0][nt]);
        oc[1][nt] = MFMA16(a1, bw, oc[1][nt]);
      }
    }
    #pragma unroll
    for (int mt=0; mt<2; ++mt)
      #pragma unroll
      for (int nt=0; nt<8; ++nt){
        int col = w*256 + nh*128 + nt*16 + l16;
        float bv = bo[col];
        #pragma unroll
        for (int r=0;r<4;r++){
          long row = rowb + mt*16 + g*4 + r;
          __builtin_nontemporal_store(oc[mt][nt][r] + bv, &out[row*OUT_ + col]);
        }
      }
  }
  #undef IDX128
  #undef IDXV
}

extern "C" void kernel_launch(void* const* d_in, const int* in_sizes, int n_in,
                              void* d_out, int out_size, void* d_ws, size_t ws_size,
                              hipStream_t stream) {
  const float* hidden = (const float*)d_in[0];
  const float* Wp     = (const float*)d_in[1];
  const float* bp     = (const float*)d_in[2];
  const float* Wo     = (const float*)d_in[3];
  const float* bo     = (const float*)d_in[4];
  float* out    = (float*)d_out;
  float* fstate = out + (long)M_ * OUT_;

  char* w = (char*)d_ws;
  unsigned short* vT    = (unsigned short*)w;                     // 8 MB
  float*          Gc    = (float*)(w + 8388608);                  // 0.5 MB
  unsigned short* Ut    = (unsigned short*)(w + 8912896);         // 32 MB (also cellT)
  float*          segB  = (float*)(w + 42467328);                 // 4 MB
  float*          segG  = (float*)(w + 46661632);                 // 32 KB
  // persistent region
  unsigned short* Wot = (unsigned short*)(w + 67108864);          // 0.25 MB
  unsigned short* Wpt = (unsigned short*)(w + 67371008);          // 1 MB
  unsigned short* qbf = (unsigned short*)(w + 68419584);          // 8 MB
  unsigned short* kbf = (unsigned short*)(w + 76808192);          // 8 MB
  unsigned short* vbf = (unsigned short*)(w + 85196800);          // 8 MB
  float*          gf  = (float*)(w + 93585408);                   // 16 MB

  convT2<<<640, 256, 0, stream>>>(Wp, Wo, Wpt, Wot);
  proj_mfma4<<<512, 512, 0, stream>>>(hidden, Wpt, bp, qbf, kbf, gf, vbf);
  prep_cs<<<dim3(NC, B_), 256, 0, stream>>>(gf, qbf, kbf, vbf, vT, Gc, Ut);
  seqstate_a<<<dim3(16, 8, B_), 256, 0, stream>>>(Gc, Ut, segB, segG);
  seqstate_b<<<dim3(16, 8, B_), 256, 0, stream>>>(Gc, Ut, segB, segG, fstate);
  chunkout_out<<<dim3(NC, B_), 256, 0, stream>>>(qbf, kbf, vT, Ut, Wot, bo, out);
}